// Round 1
// baseline (213.670 us; speedup 1.0000x reference)
//
#include <hip/hip_runtime.h>
#include <math.h>

#define Vn 3
#define Bn 2
#define Cn 16
#define Hn 128
#define Wn 128
#define Dn 32
#define HWn (Hn*Wn)

// ---------------------------------------------------------------------------
// Stage 1: per (src_view, batch) projection matrices
// proj = src_KK @ src_w2c @ inv(ref_KK @ ref_w2c); store rot(9)+trans(3)
// ---------------------------------------------------------------------------
__global__ void setup_proj_kernel(const float* __restrict__ intr,
                                  const float* __restrict__ c2w,
                                  float* __restrict__ proj) {
    int t = threadIdx.x;
    if (t >= (Vn - 1) * Bn) return;
    int vi = t / Bn;      // 0..V-2  (src view index - 1)
    int b  = t % Bn;
    int v  = vi + 1;

    const float* Ks = intr + (v * Bn + b) * 9;
    const float* Cs = c2w  + (v * Bn + b) * 16;
    const float* Kr = intr + (0 * Bn + b) * 9;
    const float* Cr = c2w  + (0 * Bn + b) * 16;

    float Ms[9], ms[3], Mr[9], mr[3];
    // For X in {src, ref}: w2c = [[R^T, -R^T t],[0,1]];  KK = [[K, tw],[0,1]]
    // M = K @ R^T ; m = K @ tw + tw  where tw = -R^T t
    for (int which = 0; which < 2; which++) {
        const float* K = which ? Kr : Ks;
        const float* C = which ? Cr : Cs;
        float* M  = which ? Mr : Ms;
        float* mv = which ? mr : ms;
        float R[9], tt[3];
        for (int i = 0; i < 3; i++) {
            for (int j = 0; j < 3; j++) R[i*3+j] = C[i*4+j];
            tt[i] = C[i*4+3];
        }
        float tw[3];
        for (int i = 0; i < 3; i++)
            tw[i] = -(R[0*3+i]*tt[0] + R[1*3+i]*tt[1] + R[2*3+i]*tt[2]);
        for (int i = 0; i < 3; i++)
            for (int j = 0; j < 3; j++)
                M[i*3+j] = K[i*3+0]*R[j*3+0] + K[i*3+1]*R[j*3+1] + K[i*3+2]*R[j*3+2];
        for (int i = 0; i < 3; i++)
            mv[i] = K[i*3+0]*tw[0] + K[i*3+1]*tw[1] + K[i*3+2]*tw[2] + tw[i];
    }

    // inv(Mr) via adjugate
    float a = Mr[0], bb = Mr[1], c = Mr[2];
    float d = Mr[3], e  = Mr[4], f = Mr[5];
    float g = Mr[6], h  = Mr[7], i2 = Mr[8];
    float A_ = (e*i2 - f*h), B_ = (f*g - d*i2), C_ = (d*h - e*g);
    float det = a*A_ + bb*B_ + c*C_;
    float id = 1.0f / det;
    float inv[9];
    inv[0] = A_*id;            inv[1] = (c*h - bb*i2)*id;  inv[2] = (bb*f - c*e)*id;
    inv[3] = B_*id;            inv[4] = (a*i2 - c*g)*id;   inv[5] = (c*d - a*f)*id;
    inv[6] = C_*id;            inv[7] = (bb*g - a*h)*id;   inv[8] = (a*e - bb*d)*id;

    float rot[9], trans[3];
    for (int r = 0; r < 3; r++)
        for (int cc = 0; cc < 3; cc++)
            rot[r*3+cc] = Ms[r*3+0]*inv[0*3+cc] + Ms[r*3+1]*inv[1*3+cc] + Ms[r*3+2]*inv[2*3+cc];
    for (int r = 0; r < 3; r++)
        trans[r] = ms[r] - (rot[r*3+0]*mr[0] + rot[r*3+1]*mr[1] + rot[r*3+2]*mr[2]);

    float* o = proj + t * 12;
    for (int k = 0; k < 9; k++) o[k] = rot[k];
    for (int k = 0; k < 3; k++) o[9+k] = trans[k];
}

// ---------------------------------------------------------------------------
// Stage 2: cost volume (B,D,H,W): warp both src views, cumsum, min L2 cost
// ---------------------------------------------------------------------------
__global__ void cost_kernel(const float* __restrict__ feat,
                            const float* __restrict__ depth,
                            const float* __restrict__ proj,
                            float* __restrict__ cv) {
    int idx = blockIdx.x * blockDim.x + threadIdx.x;   // ((b*D+d)*H+y)*W+x
    if (idx >= Bn * Dn * HWn) return;
    int x = idx % Wn;
    int y = (idx / Wn) % Hn;
    int d = (idx / HWn) % Dn;
    int b = idx / (Dn * HWn);
    (void)d;

    float dep = depth[idx];

    float ref[Cn];
    const float* rf = feat + (size_t)(0 * Bn + b) * Cn * HWn + y * Wn + x;
    #pragma unroll
    for (int c = 0; c < Cn; c++) ref[c] = rf[(size_t)c * HWn];

    float cum[Cn];
    #pragma unroll
    for (int c = 0; c < Cn; c++) cum[c] = 0.0f;

    const float fxp = (float)x, fyp = (float)y;
    float best = 3.402823e38f;

    for (int vi = 0; vi < Vn - 1; vi++) {
        const float* P = proj + (vi * Bn + b) * 12;
        float rx = P[0]*fxp + P[1]*fyp + P[2];
        float ry = P[3]*fxp + P[4]*fyp + P[5];
        float rz = P[6]*fxp + P[7]*fyp + P[8];
        float px = rx * dep + P[9];
        float py = ry * dep + P[10];
        float pz = rz * dep + P[11];
        float inz = 1.0f / pz;
        // grid normalize with (W-1)/2 then grid_sample denorm with W/2 - 0.5
        float sx = px * inz * ((float)Wn / (float)(Wn - 1)) - 0.5f;
        float sy = py * inz * ((float)Hn / (float)(Hn - 1)) - 0.5f;

        float x0f = floorf(sx), y0f = floorf(sy);
        float fx = sx - x0f, fy = sy - y0f;
        int x0 = (int)x0f, y0 = (int)y0f;
        int x1 = x0 + 1, y1 = y0 + 1;
        bool vx0 = (x0 >= 0) && (x0 < Wn);
        bool vx1 = (x1 >= 0) && (x1 < Wn);
        bool vy0 = (y0 >= 0) && (y0 < Hn);
        bool vy1 = (y1 >= 0) && (y1 < Hn);
        int xc0 = min(max(x0, 0), Wn - 1), xc1 = min(max(x1, 0), Wn - 1);
        int yc0 = min(max(y0, 0), Hn - 1), yc1 = min(max(y1, 0), Hn - 1);
        float w00 = (1.0f - fx) * (1.0f - fy);
        float w01 = fx * (1.0f - fy);
        float w10 = (1.0f - fx) * fy;
        float w11 = fx * fy;
        float m00 = (vx0 && vy0) ? w00 : 0.0f;
        float m01 = (vx1 && vy0) ? w01 : 0.0f;
        float m10 = (vx0 && vy1) ? w10 : 0.0f;
        float m11 = (vx1 && vy1) ? w11 : 0.0f;
        int o00 = yc0 * Wn + xc0, o01 = yc0 * Wn + xc1;
        int o10 = yc1 * Wn + xc0, o11 = yc1 * Wn + xc1;

        const float* sf = feat + (size_t)((vi + 1) * Bn + b) * Cn * HWn;
        float s = 0.0f;
        #pragma unroll
        for (int c = 0; c < Cn; c++) {
            const float* sc = sf + (size_t)c * HWn;
            float val = m00 * sc[o00] + m01 * sc[o01] + m10 * sc[o10] + m11 * sc[o11];
            cum[c] += val;
            float df = ref[c] - cum[c];
            s += df * df;
        }
        float cost = sqrtf(s);
        best = fminf(best, cost);
    }
    cv[idx] = best;
}

// ---------------------------------------------------------------------------
// Stage 3: w_feat (B,25,H,W): 5x5 neighborhood feature-diff L2 norms (zero-pad)
// ---------------------------------------------------------------------------
__global__ void wfeat_kernel(const float* __restrict__ feat,
                             float* __restrict__ wf) {
    int idx = blockIdx.x * blockDim.x + threadIdx.x;   // (b*H+y)*W+x
    if (idx >= Bn * HWn) return;
    int x = idx % Wn;
    int y = (idx / Wn) % Hn;
    int b = idx / HWn;

    float ctr[Cn];
    const float* rf = feat + (size_t)b * Cn * HWn + y * Wn + x;  // view 0
    #pragma unroll
    for (int c = 0; c < Cn; c++) ctr[c] = rf[(size_t)c * HWn];

    for (int k = 0; k < 25; k++) {
        int dy = k / 5 - 2, dx = k % 5 - 2;
        int ny = y + dy, nx = x + dx;
        bool ok = (ny >= 0) && (ny < Hn) && (nx >= 0) && (nx < Wn);
        float s = 0.0f;
        if (ok) {
            const float* nf = feat + (size_t)b * Cn * HWn + ny * Wn + nx;
            #pragma unroll
            for (int c = 0; c < Cn; c++) {
                float df = nf[(size_t)c * HWn] - ctr[c];
                s += df * df;
            }
        } else {
            // padded value is 0 -> diff = -center
            #pragma unroll
            for (int c = 0; c < Cn; c++) s += ctr[c] * ctr[c];
        }
        wf[(size_t)(b * 25 + k) * HWn + y * Wn + x] = sqrtf(s);
    }
}

// ---------------------------------------------------------------------------
// Stage 4: agg (B,D,H,W): softmax over 25 |d-depth diffs| * w_feat * cost
// ---------------------------------------------------------------------------
__global__ void agg_kernel(const float* __restrict__ cv,
                           const float* __restrict__ depth,
                           const float* __restrict__ wf,
                           float* __restrict__ agg) {
    int idx = blockIdx.x * blockDim.x + threadIdx.x;   // ((b*D+d)*H+y)*W+x
    if (idx >= Bn * Dn * HWn) return;
    int x = idx % Wn;
    int y = (idx / Wn) % Hn;
    int d = (idx / HWn) % Dn;
    int b = idx / (Dn * HWn);

    float ctr = depth[idx];
    const size_t plane = (size_t)(b * Dn + d) * HWn;

    // pass 1: max of |dnb - ctr| (OOB -> |0 - ctr|)
    float mx = -3.402823e38f;
    #pragma unroll
    for (int k = 0; k < 25; k++) {
        int ny = y + k / 5 - 2, nx = x + k % 5 - 2;
        bool ok = (ny >= 0) && (ny < Hn) && (nx >= 0) && (nx < Wn);
        float dn = ok ? depth[plane + ny * Wn + nx] : 0.0f;
        mx = fmaxf(mx, fabsf(dn - ctr));
    }
    // pass 2: softmax-weighted sum
    float den = 0.0f, num = 0.0f;
    #pragma unroll
    for (int k = 0; k < 25; k++) {
        int ny = y + k / 5 - 2, nx = x + k % 5 - 2;
        bool ok = (ny >= 0) && (ny < Hn) && (nx >= 0) && (nx < Wn);
        int off = ny * Wn + nx;
        float dn = ok ? depth[plane + off] : 0.0f;
        float e = __expf(fabsf(dn - ctr) - mx);
        den += e;
        float cn = ok ? cv[plane + off] : 0.0f;
        float w = wf[(size_t)(b * 25 + k) * HWn + y * Wn + x];
        num += cn * e * w;
    }
    agg[idx] = num / den;
}

// ---------------------------------------------------------------------------
// Stage 5: softmax over D + expectation -> out (B,H,W)
// ---------------------------------------------------------------------------
__global__ void final_kernel(const float* __restrict__ agg,
                             const float* __restrict__ depth,
                             float* __restrict__ out) {
    int idx = blockIdx.x * blockDim.x + threadIdx.x;   // (b*H+y)*W+x
    if (idx >= Bn * HWn) return;
    int b = idx / HWn;
    int p = idx % HWn;

    float mx = -3.402823e38f;
    #pragma unroll
    for (int d = 0; d < Dn; d++)
        mx = fmaxf(mx, agg[(size_t)(b * Dn + d) * HWn + p]);
    float den = 0.0f, num = 0.0f;
    #pragma unroll
    for (int d = 0; d < Dn; d++) {
        size_t o = (size_t)(b * Dn + d) * HWn + p;
        float e = __expf(agg[o] - mx);
        den += e;
        num += e * depth[o];
    }
    out[idx] = num / den;
}

// ---------------------------------------------------------------------------
extern "C" void kernel_launch(void* const* d_in, const int* in_sizes, int n_in,
                              void* d_out, int out_size, void* d_ws, size_t ws_size,
                              hipStream_t stream) {
    const float* feat  = (const float*)d_in[0];   // (V,B,C,H,W)
    const float* intr  = (const float*)d_in[1];   // (V,B,3,3)
    const float* c2w   = (const float*)d_in[2];   // (V,B,4,4)
    const float* depth = (const float*)d_in[3];   // (B,D,H,W)
    float* out = (float*)d_out;                   // (B,H,W)

    float* ws   = (float*)d_ws;
    float* proj = ws;                              // 48 floats (pad to 64)
    float* cv   = ws + 64;                         // B*D*H*W = 1048576
    float* wf   = cv + (size_t)Bn * Dn * HWn;      // B*25*H*W = 819200
    float* agg  = wf + (size_t)Bn * 25 * HWn;      // B*D*H*W = 1048576

    setup_proj_kernel<<<1, 64, 0, stream>>>(intr, c2w, proj);

    int n_cost = Bn * Dn * HWn;
    cost_kernel<<<(n_cost + 255) / 256, 256, 0, stream>>>(feat, depth, proj, cv);

    int n_pix = Bn * HWn;
    wfeat_kernel<<<(n_pix + 255) / 256, 256, 0, stream>>>(feat, wf);

    agg_kernel<<<(n_cost + 255) / 256, 256, 0, stream>>>(cv, depth, wf, agg);

    final_kernel<<<(n_pix + 255) / 256, 256, 0, stream>>>(agg, depth, out);
}

// Round 2
// 190.955 us; speedup vs baseline: 1.1190x; 1.1190x over previous
//
#include <hip/hip_runtime.h>
#include <math.h>

#define Vn 3
#define Bn 2
#define Cn 16
#define Hn 128
#define Wn 128
#define Dn 32
#define HWn (Hn*Wn)

__device__ __forceinline__ void load16(float* r, const float* p) {
    const float4* q = (const float4*)p;
    float4 a = q[0], b = q[1], c = q[2], d = q[3];
    r[0]=a.x; r[1]=a.y; r[2]=a.z; r[3]=a.w;
    r[4]=b.x; r[5]=b.y; r[6]=b.z; r[7]=b.w;
    r[8]=c.x; r[9]=c.y; r[10]=c.z; r[11]=c.w;
    r[12]=d.x; r[13]=d.y; r[14]=d.z; r[15]=d.w;
}

// ---------------------------------------------------------------------------
// Stage 0: transpose features (V,B,C,H,W) -> (V,B,H,W,C)  channel-contiguous
// ---------------------------------------------------------------------------
__global__ void transpose_kernel(const float* __restrict__ feat,
                                 float* __restrict__ featT) {
    int idx = blockIdx.x * blockDim.x + threadIdx.x;   // vb*HWn + p
    if (idx >= Vn * Bn * HWn) return;
    int p  = idx % HWn;
    int vb = idx / HWn;
    const float* src = feat + (size_t)vb * Cn * HWn + p;
    float v[Cn];
    #pragma unroll
    for (int c = 0; c < Cn; c++) v[c] = src[(size_t)c * HWn];  // coalesced per c
    float4* dst = (float4*)(featT + (size_t)idx * Cn);
    dst[0] = make_float4(v[0], v[1], v[2], v[3]);
    dst[1] = make_float4(v[4], v[5], v[6], v[7]);
    dst[2] = make_float4(v[8], v[9], v[10], v[11]);
    dst[3] = make_float4(v[12], v[13], v[14], v[15]);
}

// ---------------------------------------------------------------------------
// Stage 1: per (src_view, batch) projection matrices
// ---------------------------------------------------------------------------
__global__ void setup_proj_kernel(const float* __restrict__ intr,
                                  const float* __restrict__ c2w,
                                  float* __restrict__ proj) {
    int t = threadIdx.x;
    if (t >= (Vn - 1) * Bn) return;
    int vi = t / Bn;
    int b  = t % Bn;
    int v  = vi + 1;

    const float* Ks = intr + (v * Bn + b) * 9;
    const float* Cs = c2w  + (v * Bn + b) * 16;
    const float* Kr = intr + (0 * Bn + b) * 9;
    const float* Cr = c2w  + (0 * Bn + b) * 16;

    float Ms[9], ms[3], Mr[9], mr[3];
    for (int which = 0; which < 2; which++) {
        const float* K = which ? Kr : Ks;
        const float* C = which ? Cr : Cs;
        float* M  = which ? Mr : Ms;
        float* mv = which ? mr : ms;
        float R[9], tt[3];
        for (int i = 0; i < 3; i++) {
            for (int j = 0; j < 3; j++) R[i*3+j] = C[i*4+j];
            tt[i] = C[i*4+3];
        }
        float tw[3];
        for (int i = 0; i < 3; i++)
            tw[i] = -(R[0*3+i]*tt[0] + R[1*3+i]*tt[1] + R[2*3+i]*tt[2]);
        for (int i = 0; i < 3; i++)
            for (int j = 0; j < 3; j++)
                M[i*3+j] = K[i*3+0]*R[j*3+0] + K[i*3+1]*R[j*3+1] + K[i*3+2]*R[j*3+2];
        for (int i = 0; i < 3; i++)
            mv[i] = K[i*3+0]*tw[0] + K[i*3+1]*tw[1] + K[i*3+2]*tw[2] + tw[i];
    }

    float a = Mr[0], bb = Mr[1], c = Mr[2];
    float d = Mr[3], e  = Mr[4], f = Mr[5];
    float g = Mr[6], h  = Mr[7], i2 = Mr[8];
    float A_ = (e*i2 - f*h), B_ = (f*g - d*i2), C_ = (d*h - e*g);
    float det = a*A_ + bb*B_ + c*C_;
    float id = 1.0f / det;
    float inv[9];
    inv[0] = A_*id;            inv[1] = (c*h - bb*i2)*id;  inv[2] = (bb*f - c*e)*id;
    inv[3] = B_*id;            inv[4] = (a*i2 - c*g)*id;   inv[5] = (c*d - a*f)*id;
    inv[6] = C_*id;            inv[7] = (bb*g - a*h)*id;   inv[8] = (a*e - bb*d)*id;

    float rot[9], trans[3];
    for (int r = 0; r < 3; r++)
        for (int cc = 0; cc < 3; cc++)
            rot[r*3+cc] = Ms[r*3+0]*inv[0*3+cc] + Ms[r*3+1]*inv[1*3+cc] + Ms[r*3+2]*inv[2*3+cc];
    for (int r = 0; r < 3; r++)
        trans[r] = ms[r] - (rot[r*3+0]*mr[0] + rot[r*3+1]*mr[1] + rot[r*3+2]*mr[2]);

    float* o = proj + t * 12;
    for (int k = 0; k < 9; k++) o[k] = rot[k];
    for (int k = 0; k < 3; k++) o[9+k] = trans[k];
}

// ---------------------------------------------------------------------------
// Stage 2: cost volume (B,D,H,W) using channel-contiguous featT
// ---------------------------------------------------------------------------
__global__ void cost_kernel(const float* __restrict__ featT,
                            const float* __restrict__ depth,
                            const float* __restrict__ proj,
                            float* __restrict__ cv) {
    int idx = blockIdx.x * blockDim.x + threadIdx.x;   // ((b*D+d)*H+y)*W+x
    if (idx >= Bn * Dn * HWn) return;
    int x = idx % Wn;
    int y = (idx / Wn) % Hn;
    int b = idx / (Dn * HWn);

    float dep = depth[idx];

    float ref[Cn];
    load16(ref, featT + ((size_t)(0 * Bn + b) * HWn + y * Wn + x) * Cn);

    float cum[Cn];
    #pragma unroll
    for (int c = 0; c < Cn; c++) cum[c] = 0.0f;

    const float fxp = (float)x, fyp = (float)y;
    float best = 3.402823e38f;

    #pragma unroll
    for (int vi = 0; vi < Vn - 1; vi++) {
        const float* P = proj + (vi * Bn + b) * 12;
        float rx = P[0]*fxp + P[1]*fyp + P[2];
        float ry = P[3]*fxp + P[4]*fyp + P[5];
        float rz = P[6]*fxp + P[7]*fyp + P[8];
        float px = rx * dep + P[9];
        float py = ry * dep + P[10];
        float pz = rz * dep + P[11];
        float inz = 1.0f / pz;
        float sx = px * inz * ((float)Wn / (float)(Wn - 1)) - 0.5f;
        float sy = py * inz * ((float)Hn / (float)(Hn - 1)) - 0.5f;

        float x0f = floorf(sx), y0f = floorf(sy);
        float fx = sx - x0f, fy = sy - y0f;
        int x0 = (int)x0f, y0 = (int)y0f;
        int x1 = x0 + 1, y1 = y0 + 1;
        bool vx0 = (x0 >= 0) && (x0 < Wn);
        bool vx1 = (x1 >= 0) && (x1 < Wn);
        bool vy0 = (y0 >= 0) && (y0 < Hn);
        bool vy1 = (y1 >= 0) && (y1 < Hn);
        int xc0 = min(max(x0, 0), Wn - 1), xc1 = min(max(x1, 0), Wn - 1);
        int yc0 = min(max(y0, 0), Hn - 1), yc1 = min(max(y1, 0), Hn - 1);
        float w00 = (1.0f - fx) * (1.0f - fy);
        float w01 = fx * (1.0f - fy);
        float w10 = (1.0f - fx) * fy;
        float w11 = fx * fy;
        float m00 = (vx0 && vy0) ? w00 : 0.0f;
        float m01 = (vx1 && vy0) ? w01 : 0.0f;
        float m10 = (vx0 && vy1) ? w10 : 0.0f;
        float m11 = (vx1 && vy1) ? w11 : 0.0f;
        size_t o00 = (size_t)(yc0 * Wn + xc0) * Cn, o01 = (size_t)(yc0 * Wn + xc1) * Cn;
        size_t o10 = (size_t)(yc1 * Wn + xc0) * Cn, o11 = (size_t)(yc1 * Wn + xc1) * Cn;

        const float* sf = featT + (size_t)((vi + 1) * Bn + b) * HWn * Cn;
        float t00[Cn], t01[Cn], t10[Cn], t11[Cn];
        load16(t00, sf + o00);
        load16(t01, sf + o01);
        load16(t10, sf + o10);
        load16(t11, sf + o11);

        float s = 0.0f;
        #pragma unroll
        for (int c = 0; c < Cn; c++) {
            float val = m00 * t00[c] + m01 * t01[c] + m10 * t10[c] + m11 * t11[c];
            cum[c] += val;
            float df = ref[c] - cum[c];
            s += df * df;
        }
        float cost = sqrtf(s);
        best = fminf(best, cost);
    }
    cv[idx] = best;
}

// ---------------------------------------------------------------------------
// Stage 3: w_feat (B,25,H,W) using channel-contiguous featT (view 0)
// ---------------------------------------------------------------------------
__global__ void wfeat_kernel(const float* __restrict__ featT,
                             float* __restrict__ wf) {
    int idx = blockIdx.x * blockDim.x + threadIdx.x;   // (b*H+y)*W+x
    if (idx >= Bn * HWn) return;
    int x = idx % Wn;
    int y = (idx / Wn) % Hn;
    int b = idx / HWn;

    const float* base = featT + (size_t)(0 * Bn + b) * HWn * Cn;
    float ctr[Cn];
    load16(ctr, base + (size_t)(y * Wn + x) * Cn);

    float ctr2 = 0.0f;
    #pragma unroll
    for (int c = 0; c < Cn; c++) ctr2 += ctr[c] * ctr[c];

    #pragma unroll
    for (int k = 0; k < 25; k++) {
        int dy = k / 5 - 2, dx = k % 5 - 2;
        int ny = y + dy, nx = x + dx;
        bool ok = (ny >= 0) && (ny < Hn) && (nx >= 0) && (nx < Wn);
        float s;
        if (ok) {
            float nb[Cn];
            load16(nb, base + (size_t)(ny * Wn + nx) * Cn);
            s = 0.0f;
            #pragma unroll
            for (int c = 0; c < Cn; c++) {
                float df = nb[c] - ctr[c];
                s += df * df;
            }
        } else {
            s = ctr2;   // padded value 0 -> diff = -center
        }
        wf[(size_t)(b * 25 + k) * HWn + y * Wn + x] = sqrtf(s);
    }
}

// ---------------------------------------------------------------------------
// Stage 4: agg (B,D,H,W): softmax over 25 |depth diffs| * w_feat * cost
// ---------------------------------------------------------------------------
__global__ void agg_kernel(const float* __restrict__ cv,
                           const float* __restrict__ depth,
                           const float* __restrict__ wf,
                           float* __restrict__ agg) {
    int idx = blockIdx.x * blockDim.x + threadIdx.x;   // ((b*D+d)*H+y)*W+x
    if (idx >= Bn * Dn * HWn) return;
    int x = idx % Wn;
    int y = (idx / Wn) % Hn;
    int d = (idx / HWn) % Dn;
    int b = idx / (Dn * HWn);

    float ctr = depth[idx];
    const size_t plane = (size_t)(b * Dn + d) * HWn;

    // pass 1: |dnb - ctr| cached in registers; track max
    float aarr[25];
    float mx = -3.402823e38f;
    #pragma unroll
    for (int k = 0; k < 25; k++) {
        int ny = y + k / 5 - 2, nx = x + k % 5 - 2;
        bool ok = (ny >= 0) && (ny < Hn) && (nx >= 0) && (nx < Wn);
        float dn = ok ? depth[plane + ny * Wn + nx] : 0.0f;
        aarr[k] = fabsf(dn - ctr);
        mx = fmaxf(mx, aarr[k]);
    }
    // pass 2: softmax-weighted sum
    float den = 0.0f, num = 0.0f;
    #pragma unroll
    for (int k = 0; k < 25; k++) {
        int ny = y + k / 5 - 2, nx = x + k % 5 - 2;
        bool ok = (ny >= 0) && (ny < Hn) && (nx >= 0) && (nx < Wn);
        float e = __expf(aarr[k] - mx);
        den += e;
        float cn = ok ? cv[plane + ny * Wn + nx] : 0.0f;
        float w = wf[(size_t)(b * 25 + k) * HWn + y * Wn + x];
        num += cn * e * w;
    }
    agg[idx] = num / den;
}

// ---------------------------------------------------------------------------
// Stage 5: softmax over D + expectation -> out (B,H,W)
// ---------------------------------------------------------------------------
__global__ void final_kernel(const float* __restrict__ agg,
                             const float* __restrict__ depth,
                             float* __restrict__ out) {
    int idx = blockIdx.x * blockDim.x + threadIdx.x;   // (b*H+y)*W+x
    if (idx >= Bn * HWn) return;
    int b = idx / HWn;
    int p = idx % HWn;

    float mx = -3.402823e38f;
    #pragma unroll
    for (int d = 0; d < Dn; d++)
        mx = fmaxf(mx, agg[(size_t)(b * Dn + d) * HWn + p]);
    float den = 0.0f, num = 0.0f;
    #pragma unroll
    for (int d = 0; d < Dn; d++) {
        size_t o = (size_t)(b * Dn + d) * HWn + p;
        float e = __expf(agg[o] - mx);
        den += e;
        num += e * depth[o];
    }
    out[idx] = num / den;
}

// ---------------------------------------------------------------------------
extern "C" void kernel_launch(void* const* d_in, const int* in_sizes, int n_in,
                              void* d_out, int out_size, void* d_ws, size_t ws_size,
                              hipStream_t stream) {
    const float* feat  = (const float*)d_in[0];   // (V,B,C,H,W)
    const float* intr  = (const float*)d_in[1];   // (V,B,3,3)
    const float* c2w   = (const float*)d_in[2];   // (V,B,4,4)
    const float* depth = (const float*)d_in[3];   // (B,D,H,W)
    float* out = (float*)d_out;                   // (B,H,W)

    float* ws    = (float*)d_ws;
    float* proj  = ws;                                  // 64 floats
    float* featT = ws + 64;                             // V*B*HW*C = 1572864
    float* cv    = featT + (size_t)Vn * Bn * HWn * Cn;  // B*D*HW   = 1048576
    float* wf    = cv + (size_t)Bn * Dn * HWn;          // B*25*HW  = 819200
    float* agg   = wf + (size_t)Bn * 25 * HWn;          // B*D*HW   = 1048576

    int n_tr = Vn * Bn * HWn;
    transpose_kernel<<<(n_tr + 255) / 256, 256, 0, stream>>>(feat, featT);

    setup_proj_kernel<<<1, 64, 0, stream>>>(intr, c2w, proj);

    int n_cost = Bn * Dn * HWn;
    cost_kernel<<<(n_cost + 255) / 256, 256, 0, stream>>>(featT, depth, proj, cv);

    int n_pix = Bn * HWn;
    wfeat_kernel<<<(n_pix + 255) / 256, 256, 0, stream>>>(featT, wf);

    agg_kernel<<<(n_cost + 255) / 256, 256, 0, stream>>>(cv, depth, wf, agg);

    final_kernel<<<(n_pix + 255) / 256, 256, 0, stream>>>(agg, depth, out);
}

// Round 4
// 153.868 us; speedup vs baseline: 1.3887x; 1.2410x over previous
//
#include <hip/hip_runtime.h>
#include <hip/hip_fp16.h>
#include <math.h>

#define Vn 3
#define Bn 2
#define Cn 16
#define Hn 128
#define Wn 128
#define Dn 32
#define HWn (Hn*Wn)
#define KD 4          // depths per thread in cost kernel
#define PX 8          // pixels per block in fused agg kernel

// load 16 halfs (one pixel, 32B) -> 16 floats
__device__ __forceinline__ void loadC(float* r, const __half* p) {
    union { float4 f; __half2 h[4]; } u0, u1;
    u0.f = ((const float4*)p)[0];
    u1.f = ((const float4*)p)[1];
    #pragma unroll
    for (int j = 0; j < 4; j++) {
        float2 a = __half22float2(u0.h[j]);
        r[2*j]   = a.x; r[2*j+1] = a.y;
        float2 b = __half22float2(u1.h[j]);
        r[8+2*j] = b.x; r[8+2*j+1] = b.y;
    }
}

// ---------------------------------------------------------------------------
// Stage 0: transpose features (V,B,C,H,W) fp32 -> (V,B,H,W,C) fp16
// ---------------------------------------------------------------------------
__global__ void transpose_kernel(const float* __restrict__ feat,
                                 __half* __restrict__ featH) {
    int idx = blockIdx.x * blockDim.x + threadIdx.x;   // vb*HWn + p
    if (idx >= Vn * Bn * HWn) return;
    int p  = idx % HWn;
    int vb = idx / HWn;
    const float* src = feat + (size_t)vb * Cn * HWn + p;
    union { float4 f[2]; __half h[16]; } u;
    #pragma unroll
    for (int c = 0; c < Cn; c++) u.h[c] = __float2half(src[(size_t)c * HWn]);
    float4* dst = (float4*)(featH + (size_t)idx * Cn);
    dst[0] = u.f[0];
    dst[1] = u.f[1];
}

// ---------------------------------------------------------------------------
// Stage 1: per (src_view, batch) projection matrices
// ---------------------------------------------------------------------------
__global__ void setup_proj_kernel(const float* __restrict__ intr,
                                  const float* __restrict__ c2w,
                                  float* __restrict__ proj) {
    int t = threadIdx.x;
    if (t >= (Vn - 1) * Bn) return;
    int vi = t / Bn;
    int b  = t % Bn;
    int v  = vi + 1;

    const float* Ks = intr + (v * Bn + b) * 9;
    const float* Cs = c2w  + (v * Bn + b) * 16;
    const float* Kr = intr + (0 * Bn + b) * 9;
    const float* Cr = c2w  + (0 * Bn + b) * 16;

    float Ms[9], ms[3], Mr[9], mr[3];
    for (int which = 0; which < 2; which++) {
        const float* K = which ? Kr : Ks;
        const float* C = which ? Cr : Cs;
        float* M  = which ? Mr : Ms;
        float* mv = which ? mr : ms;
        float R[9], tt[3];
        for (int i = 0; i < 3; i++) {
            for (int j = 0; j < 3; j++) R[i*3+j] = C[i*4+j];
            tt[i] = C[i*4+3];
        }
        float tw[3];
        for (int i = 0; i < 3; i++)
            tw[i] = -(R[0*3+i]*tt[0] + R[1*3+i]*tt[1] + R[2*3+i]*tt[2]);
        for (int i = 0; i < 3; i++)
            for (int j = 0; j < 3; j++)
                M[i*3+j] = K[i*3+0]*R[j*3+0] + K[i*3+1]*R[j*3+1] + K[i*3+2]*R[j*3+2];
        for (int i = 0; i < 3; i++)
            mv[i] = K[i*3+0]*tw[0] + K[i*3+1]*tw[1] + K[i*3+2]*tw[2] + tw[i];
    }

    float a = Mr[0], bb = Mr[1], c = Mr[2];
    float d = Mr[3], e  = Mr[4], f = Mr[5];
    float g = Mr[6], h  = Mr[7], i2 = Mr[8];
    float A_ = (e*i2 - f*h), B_ = (f*g - d*i2), C_ = (d*h - e*g);
    float det = a*A_ + bb*B_ + c*C_;
    float id = 1.0f / det;
    float inv[9];
    inv[0] = A_*id;            inv[1] = (c*h - bb*i2)*id;  inv[2] = (bb*f - c*e)*id;
    inv[3] = B_*id;            inv[4] = (a*i2 - c*g)*id;   inv[5] = (c*d - a*f)*id;
    inv[6] = C_*id;            inv[7] = (bb*g - a*h)*id;   inv[8] = (a*e - bb*d)*id;

    float rot[9], trans[3];
    for (int r = 0; r < 3; r++)
        for (int cc = 0; cc < 3; cc++)
            rot[r*3+cc] = Ms[r*3+0]*inv[0*3+cc] + Ms[r*3+1]*inv[1*3+cc] + Ms[r*3+2]*inv[2*3+cc];
    for (int r = 0; r < 3; r++)
        trans[r] = ms[r] - (rot[r*3+0]*mr[0] + rot[r*3+1]*mr[1] + rot[r*3+2]*mr[2]);

    float* o = proj + t * 12;
    for (int k = 0; k < 9; k++) o[k] = rot[k];
    for (int k = 0; k < 3; k++) o[9+k] = trans[k];
}

// ---------------------------------------------------------------------------
// Stage 2: cost volume (B,D,H,W). One thread = KD depths of one pixel.
// NOTE: no __launch_bounds__ — KD=4 needs ~190 VGPRs; capping causes spills.
// ---------------------------------------------------------------------------
__global__ void cost_kernel(const __half* __restrict__ featH,
                            const float* __restrict__ depth,
                            const float* __restrict__ proj,
                            float* __restrict__ cv) {
    int idx = blockIdx.x * blockDim.x + threadIdx.x;   // ((b*(D/KD)+dg)*H+y)*W+x
    if (idx >= Bn * (Dn/KD) * HWn) return;
    int x  = idx % Wn;
    int y  = (idx / Wn) % Hn;
    int dg = (idx / HWn) % (Dn/KD);
    int b  = idx / ((Dn/KD) * HWn);

    float dep[KD];
    #pragma unroll
    for (int i = 0; i < KD; i++)
        dep[i] = depth[(size_t)(b * Dn + dg*KD + i) * HWn + y * Wn + x];

    float ref[Cn];
    loadC(ref, featH + ((size_t)(0 * Bn + b) * HWn + y * Wn + x) * Cn);

    float cum[KD][Cn];
    #pragma unroll
    for (int i = 0; i < KD; i++)
        #pragma unroll
        for (int c = 0; c < Cn; c++) cum[i][c] = 0.0f;

    float best[KD];
    #pragma unroll
    for (int i = 0; i < KD; i++) best[i] = 3.402823e38f;

    const float fxp = (float)x, fyp = (float)y;

    #pragma unroll
    for (int vi = 0; vi < Vn - 1; vi++) {
        const float* P = proj + (vi * Bn + b) * 12;
        float rx = P[0]*fxp + P[1]*fyp + P[2];
        float ry = P[3]*fxp + P[4]*fyp + P[5];
        float rz = P[6]*fxp + P[7]*fyp + P[8];
        const __half* sf = featH + (size_t)((vi + 1) * Bn + b) * HWn * Cn;

        #pragma unroll
        for (int i = 0; i < KD; i++) {
            float px = rx * dep[i] + P[9];
            float py = ry * dep[i] + P[10];
            float pz = rz * dep[i] + P[11];
            float inz = 1.0f / pz;
            float sx = px * inz * ((float)Wn / (float)(Wn - 1)) - 0.5f;
            float sy = py * inz * ((float)Hn / (float)(Hn - 1)) - 0.5f;

            float x0f = floorf(sx), y0f = floorf(sy);
            float fx = sx - x0f, fy = sy - y0f;
            int x0 = (int)x0f, y0 = (int)y0f;
            int x1 = x0 + 1, y1 = y0 + 1;
            bool vx0 = (x0 >= 0) && (x0 < Wn);
            bool vx1 = (x1 >= 0) && (x1 < Wn);
            bool vy0 = (y0 >= 0) && (y0 < Hn);
            bool vy1 = (y1 >= 0) && (y1 < Hn);
            int xc0 = min(max(x0, 0), Wn - 1), xc1 = min(max(x1, 0), Wn - 1);
            int yc0 = min(max(y0, 0), Hn - 1), yc1 = min(max(y1, 0), Hn - 1);
            float m00 = (vx0 && vy0) ? (1.0f - fx) * (1.0f - fy) : 0.0f;
            float m01 = (vx1 && vy0) ? fx * (1.0f - fy) : 0.0f;
            float m10 = (vx0 && vy1) ? (1.0f - fx) * fy : 0.0f;
            float m11 = (vx1 && vy1) ? fx * fy : 0.0f;

            float t00[Cn], t01[Cn], t10[Cn], t11[Cn];
            loadC(t00, sf + (size_t)(yc0 * Wn + xc0) * Cn);
            loadC(t01, sf + (size_t)(yc0 * Wn + xc1) * Cn);
            loadC(t10, sf + (size_t)(yc1 * Wn + xc0) * Cn);
            loadC(t11, sf + (size_t)(yc1 * Wn + xc1) * Cn);

            float s = 0.0f;
            #pragma unroll
            for (int c = 0; c < Cn; c++) {
                float val = m00 * t00[c] + m01 * t01[c] + m10 * t10[c] + m11 * t11[c];
                cum[i][c] += val;
                float df = ref[c] - cum[i][c];
                s += df * df;
            }
            best[i] = fminf(best[i], sqrtf(s));
        }
    }
    #pragma unroll
    for (int i = 0; i < KD; i++)
        cv[(size_t)(b * Dn + dg*KD + i) * HWn + y * Wn + x] = best[i];
}

// ---------------------------------------------------------------------------
// Stage 3: w_feat (B,25,H,W) from fp16 featH (view 0)
// ---------------------------------------------------------------------------
__global__ void wfeat_kernel(const __half* __restrict__ featH,
                             float* __restrict__ wf) {
    int idx = blockIdx.x * blockDim.x + threadIdx.x;   // (b*H+y)*W+x
    if (idx >= Bn * HWn) return;
    int x = idx % Wn;
    int y = (idx / Wn) % Hn;
    int b = idx / HWn;

    const __half* base = featH + (size_t)(0 * Bn + b) * HWn * Cn;
    float ctr[Cn];
    loadC(ctr, base + (size_t)(y * Wn + x) * Cn);

    float ctr2 = 0.0f;
    #pragma unroll
    for (int c = 0; c < Cn; c++) ctr2 += ctr[c] * ctr[c];

    #pragma unroll
    for (int k = 0; k < 25; k++) {
        int dy = k / 5 - 2, dx = k % 5 - 2;
        int ny = y + dy, nx = x + dx;
        bool ok = (ny >= 0) && (ny < Hn) && (nx >= 0) && (nx < Wn);
        float s;
        if (ok) {
            float nb[Cn];
            loadC(nb, base + (size_t)(ny * Wn + nx) * Cn);
            s = 0.0f;
            #pragma unroll
            for (int c = 0; c < Cn; c++) {
                float df = nb[c] - ctr[c];
                s += df * df;
            }
        } else {
            s = ctr2;
        }
        wf[(size_t)(b * 25 + k) * HWn + y * Wn + x] = sqrtf(s);
    }
}

// ---------------------------------------------------------------------------
// Stage 4+5 fused: agg softmax(25), then serial softmax over D + expectation.
// Block: 256 threads = 32 d x 8 px. LDS-staged neighborhoods, serial tail.
// ---------------------------------------------------------------------------
__global__ void __launch_bounds__(256)
aggfinal_kernel(const float* __restrict__ cv,
                const float* __restrict__ depth,
                const float* __restrict__ wf,
                float* __restrict__ out) {
    __shared__ float sd[Dn][5][PX + 4];   // depth neighborhood
    __shared__ float sc[Dn][5][PX + 4];   // cost neighborhood
    __shared__ float swf[25][PX];         // w_feat
    __shared__ float sagg[Dn][PX];        // per-(d,px) aggregated cost

    int bi = blockIdx.x;
    int xt = bi % (Wn / PX);
    int y  = (bi / (Wn / PX)) % Hn;
    int b  = bi / (Hn * (Wn / PX));
    int x0 = xt * PX;
    int tid = threadIdx.x;

    const int NS = Dn * 5 * (PX + 4);     // 1920
    for (int s = tid; s < NS; s += 256) {
        int d  = s / (5 * (PX + 4));
        int r  = s % (5 * (PX + 4));
        int ny = r / (PX + 4);
        int nx = r % (PX + 4);
        int gy = y - 2 + ny;
        int gx = x0 - 2 + nx;
        float dv = 0.0f, cvv = 0.0f;
        if (gy >= 0 && gy < Hn && gx >= 0 && gx < Wn) {
            size_t off = (size_t)(b * Dn + d) * HWn + gy * Wn + gx;
            dv  = depth[off];
            cvv = cv[off];
        }
        sd[d][ny][nx] = dv;
        sc[d][ny][nx] = cvv;
    }
    for (int s = tid; s < 25 * PX; s += 256) {
        int k  = s / PX;
        int xi2 = s % PX;
        swf[k][xi2] = wf[(size_t)(b * 25 + k) * HWn + y * Wn + x0 + xi2];
    }
    __syncthreads();

    int xi = tid % PX;
    int d  = tid / PX;

    float ctr = sd[d][2][xi + 2];
    float aarr[25];
    float mx = -3.402823e38f;
    #pragma unroll
    for (int k = 0; k < 25; k++) {
        float dn = sd[d][k / 5][xi + k % 5];
        aarr[k] = fabsf(dn - ctr);
        mx = fmaxf(mx, aarr[k]);
    }
    float den = 0.0f, num = 0.0f;
    #pragma unroll
    for (int k = 0; k < 25; k++) {
        float e = __expf(aarr[k] - mx);
        den += e;
        num += sc[d][k / 5][xi + k % 5] * e * swf[k][xi];
    }
    sagg[d][xi] = num / den;
    __syncthreads();

    // serial softmax over D + expectation: 8 threads, one per pixel
    if (tid < PX) {
        int p = tid;
        float m = -3.402823e38f;
        #pragma unroll
        for (int dd = 0; dd < Dn; dd++)
            m = fmaxf(m, sagg[dd][p]);
        float dn2 = 0.0f, nm2 = 0.0f;
        #pragma unroll
        for (int dd = 0; dd < Dn; dd++) {
            float e = __expf(sagg[dd][p] - m);
            dn2 += e;
            nm2 += e * sd[dd][2][p + 2];
        }
        out[(size_t)(b * Hn + y) * Wn + x0 + p] = nm2 / dn2;
    }
}

// ---------------------------------------------------------------------------
extern "C" void kernel_launch(void* const* d_in, const int* in_sizes, int n_in,
                              void* d_out, int out_size, void* d_ws, size_t ws_size,
                              hipStream_t stream) {
    const float* feat  = (const float*)d_in[0];   // (V,B,C,H,W)
    const float* intr  = (const float*)d_in[1];   // (V,B,3,3)
    const float* c2w   = (const float*)d_in[2];   // (V,B,4,4)
    const float* depth = (const float*)d_in[3];   // (B,D,H,W)
    float* out = (float*)d_out;                   // (B,H,W)

    float* ws    = (float*)d_ws;
    float* proj  = ws;                                        // 64 floats
    __half* featH = (__half*)(ws + 64);                       // V*B*HW*C halfs = 3MB
    float* cv    = ws + 64 + (Vn * Bn * HWn * Cn) / 2;        // B*D*HW floats
    float* wf    = cv + (size_t)Bn * Dn * HWn;                // B*25*HW floats

    int n_tr = Vn * Bn * HWn;
    transpose_kernel<<<(n_tr + 255) / 256, 256, 0, stream>>>(feat, featH);

    setup_proj_kernel<<<1, 64, 0, stream>>>(intr, c2w, proj);

    int n_cost = Bn * (Dn / KD) * HWn;
    cost_kernel<<<(n_cost + 255) / 256, 256, 0, stream>>>(featH, depth, proj, cv);

    int n_pix = Bn * HWn;
    wfeat_kernel<<<(n_pix + 255) / 256, 256, 0, stream>>>(featH, wf);

    int n_blk = Bn * Hn * (Wn / PX);
    aggfinal_kernel<<<n_blk, 256, 0, stream>>>(cv, depth, wf, out);
}

// Round 5
// 115.737 us; speedup vs baseline: 1.8462x; 1.3295x over previous
//
#include <hip/hip_runtime.h>
#include <hip/hip_fp16.h>
#include <math.h>

#define Vn 3
#define Bn 2
#define Cn 16
#define Hn 128
#define Wn 128
#define Dn 32
#define HWn (Hn*Wn)
#define KD 4          // depths per thread in cost kernel
#define PX 8          // pixels per block in fused agg kernel

// load 8 halfs (16B) -> 8 floats
__device__ __forceinline__ void loadC8(float* r, const __half* p) {
    union { float4 f; __half2 h[4]; } u;
    u.f = *(const float4*)p;
    #pragma unroll
    for (int j = 0; j < 4; j++) {
        float2 a = __half22float2(u.h[j]);
        r[2*j] = a.x; r[2*j+1] = a.y;
    }
}

// ---------------------------------------------------------------------------
// Stage 0: transpose features (V,B,C,H,W) fp32 -> (V,B,H,W,C) fp16
//          + block 0 threads 0..3 compute the projection matrices
// ---------------------------------------------------------------------------
__global__ void transpose_kernel(const float* __restrict__ feat,
                                 __half* __restrict__ featH,
                                 const float* __restrict__ intr,
                                 const float* __restrict__ c2w,
                                 float* __restrict__ proj) {
    int idx = blockIdx.x * blockDim.x + threadIdx.x;   // vb*HWn + p
    if (idx < Vn * Bn * HWn) {
        int p  = idx % HWn;
        int vb = idx / HWn;
        const float* src = feat + (size_t)vb * Cn * HWn + p;
        union { float4 f[2]; __half h[16]; } u;
        #pragma unroll
        for (int c = 0; c < Cn; c++) u.h[c] = __float2half(src[(size_t)c * HWn]);
        float4* dst = (float4*)(featH + (size_t)idx * Cn);
        dst[0] = u.f[0];
        dst[1] = u.f[1];
    }

    if (blockIdx.x == 0 && threadIdx.x < (Vn - 1) * Bn) {
        int t  = threadIdx.x;
        int vi = t / Bn;
        int b  = t % Bn;
        int v  = vi + 1;

        const float* Ks = intr + (v * Bn + b) * 9;
        const float* Cs = c2w  + (v * Bn + b) * 16;
        const float* Kr = intr + (0 * Bn + b) * 9;
        const float* Cr = c2w  + (0 * Bn + b) * 16;

        float Ms[9], ms[3], Mr[9], mr[3];
        for (int which = 0; which < 2; which++) {
            const float* K = which ? Kr : Ks;
            const float* C = which ? Cr : Cs;
            float* M  = which ? Mr : Ms;
            float* mv = which ? mr : ms;
            float R[9], tt[3];
            for (int i = 0; i < 3; i++) {
                for (int j = 0; j < 3; j++) R[i*3+j] = C[i*4+j];
                tt[i] = C[i*4+3];
            }
            float tw[3];
            for (int i = 0; i < 3; i++)
                tw[i] = -(R[0*3+i]*tt[0] + R[1*3+i]*tt[1] + R[2*3+i]*tt[2]);
            for (int i = 0; i < 3; i++)
                for (int j = 0; j < 3; j++)
                    M[i*3+j] = K[i*3+0]*R[j*3+0] + K[i*3+1]*R[j*3+1] + K[i*3+2]*R[j*3+2];
            for (int i = 0; i < 3; i++)
                mv[i] = K[i*3+0]*tw[0] + K[i*3+1]*tw[1] + K[i*3+2]*tw[2] + tw[i];
        }

        float a = Mr[0], bb = Mr[1], c = Mr[2];
        float d = Mr[3], e  = Mr[4], f = Mr[5];
        float g = Mr[6], h  = Mr[7], i2 = Mr[8];
        float A_ = (e*i2 - f*h), B_ = (f*g - d*i2), C_ = (d*h - e*g);
        float det = a*A_ + bb*B_ + c*C_;
        float id = 1.0f / det;
        float inv[9];
        inv[0] = A_*id;            inv[1] = (c*h - bb*i2)*id;  inv[2] = (bb*f - c*e)*id;
        inv[3] = B_*id;            inv[4] = (a*i2 - c*g)*id;   inv[5] = (c*d - a*f)*id;
        inv[6] = C_*id;            inv[7] = (bb*g - a*h)*id;   inv[8] = (a*e - bb*d)*id;

        float rot[9], trans[3];
        for (int r = 0; r < 3; r++)
            for (int cc = 0; cc < 3; cc++)
                rot[r*3+cc] = Ms[r*3+0]*inv[0*3+cc] + Ms[r*3+1]*inv[1*3+cc] + Ms[r*3+2]*inv[2*3+cc];
        for (int r = 0; r < 3; r++)
            trans[r] = ms[r] - (rot[r*3+0]*mr[0] + rot[r*3+1]*mr[1] + rot[r*3+2]*mr[2]);

        float* o = proj + t * 12;
        for (int k = 0; k < 9; k++) o[k] = rot[k];
        for (int k = 0; k < 3; k++) o[9+k] = trans[k];
    }
}

// ---------------------------------------------------------------------------
// Stage 2: cost volume (B,D,H,W). One thread = KD depths of one pixel.
// Channels processed in 2 halves of 8 to keep VGPRs ~130 (no spills).
// ---------------------------------------------------------------------------
__global__ void __launch_bounds__(256)
cost_kernel(const __half* __restrict__ featH,
            const float* __restrict__ depth,
            const float* __restrict__ proj,
            float* __restrict__ cv) {
    int idx = blockIdx.x * blockDim.x + threadIdx.x;   // ((b*(D/KD)+dg)*H+y)*W+x
    if (idx >= Bn * (Dn/KD) * HWn) return;
    int x  = idx % Wn;
    int y  = (idx / Wn) % Hn;
    int dg = (idx / HWn) % (Dn/KD);
    int b  = idx / ((Dn/KD) * HWn);

    float dep[KD];
    #pragma unroll
    for (int i = 0; i < KD; i++)
        dep[i] = depth[(size_t)(b * Dn + dg*KD + i) * HWn + y * Wn + x];

    float s[KD][2];
    #pragma unroll
    for (int i = 0; i < KD; i++) { s[i][0] = 0.0f; s[i][1] = 0.0f; }

    const float fxp = (float)x, fyp = (float)y;
    const size_t pix0 = ((size_t)(0 * Bn + b) * HWn + y * Wn + x) * Cn;

    #pragma unroll
    for (int h = 0; h < 2; h++) {
        float ref8[8];
        loadC8(ref8, featH + pix0 + h * 8);

        float cum[KD][8];
        #pragma unroll
        for (int i = 0; i < KD; i++)
            #pragma unroll
            for (int j = 0; j < 8; j++) cum[i][j] = 0.0f;

        #pragma unroll
        for (int vi = 0; vi < Vn - 1; vi++) {
            const float* P = proj + (vi * Bn + b) * 12;
            float rx = P[0]*fxp + P[1]*fyp + P[2];
            float ry = P[3]*fxp + P[4]*fyp + P[5];
            float rz = P[6]*fxp + P[7]*fyp + P[8];
            const __half* sf = featH + (size_t)((vi + 1) * Bn + b) * HWn * Cn + h * 8;

            #pragma unroll
            for (int i = 0; i < KD; i++) {
                float px = rx * dep[i] + P[9];
                float py = ry * dep[i] + P[10];
                float pz = rz * dep[i] + P[11];
                float inz = 1.0f / pz;
                float sx = px * inz * ((float)Wn / (float)(Wn - 1)) - 0.5f;
                float sy = py * inz * ((float)Hn / (float)(Hn - 1)) - 0.5f;

                float x0f = floorf(sx), y0f = floorf(sy);
                float fx = sx - x0f, fy = sy - y0f;
                int x0 = (int)x0f, y0 = (int)y0f;
                int x1 = x0 + 1, y1 = y0 + 1;
                bool vx0 = (x0 >= 0) && (x0 < Wn);
                bool vx1 = (x1 >= 0) && (x1 < Wn);
                bool vy0 = (y0 >= 0) && (y0 < Hn);
                bool vy1 = (y1 >= 0) && (y1 < Hn);
                int xc0 = min(max(x0, 0), Wn - 1), xc1 = min(max(x1, 0), Wn - 1);
                int yc0 = min(max(y0, 0), Hn - 1), yc1 = min(max(y1, 0), Hn - 1);
                float m00 = (vx0 && vy0) ? (1.0f - fx) * (1.0f - fy) : 0.0f;
                float m01 = (vx1 && vy0) ? fx * (1.0f - fy) : 0.0f;
                float m10 = (vx0 && vy1) ? (1.0f - fx) * fy : 0.0f;
                float m11 = (vx1 && vy1) ? fx * fy : 0.0f;

                float t00[8], t01[8], t10[8], t11[8];
                loadC8(t00, sf + (size_t)(yc0 * Wn + xc0) * Cn);
                loadC8(t01, sf + (size_t)(yc0 * Wn + xc1) * Cn);
                loadC8(t10, sf + (size_t)(yc1 * Wn + xc0) * Cn);
                loadC8(t11, sf + (size_t)(yc1 * Wn + xc1) * Cn);

                float acc = 0.0f;
                #pragma unroll
                for (int j = 0; j < 8; j++) {
                    float val = m00 * t00[j] + m01 * t01[j] + m10 * t10[j] + m11 * t11[j];
                    cum[i][j] += val;
                    float df = ref8[j] - cum[i][j];
                    acc += df * df;
                }
                s[i][vi] += acc;
            }
        }
    }
    #pragma unroll
    for (int i = 0; i < KD; i++)
        cv[(size_t)(b * Dn + dg*KD + i) * HWn + y * Wn + x] =
            fminf(sqrtf(s[i][0]), sqrtf(s[i][1]));
}

// ---------------------------------------------------------------------------
// Stage 3+4+5 fused: w_feat from LDS feature halo, agg softmax(25),
// serial softmax over D + expectation. Block: 256 = 32 d x 8 px.
// ---------------------------------------------------------------------------
__global__ void __launch_bounds__(256)
aggfinal_kernel(const float* __restrict__ cv,
                const float* __restrict__ depth,
                const __half* __restrict__ featH,
                float* __restrict__ out) {
    __shared__ float sd[Dn][5][PX + 4];        // depth neighborhood
    __shared__ float sc[Dn][5][PX + 4];        // cost neighborhood
    __shared__ float4 sfeatv[5][PX + 4][2];    // view-0 feature halo (fp16)
    __shared__ float swf[25][PX];              // w_feat
    __shared__ float sagg[Dn][PX];             // aggregated cost

    int bi = blockIdx.x;
    int xt = bi % (Wn / PX);
    int y  = (bi / (Wn / PX)) % Hn;
    int b  = bi / (Hn * (Wn / PX));
    int x0 = xt * PX;
    int tid = threadIdx.x;

    // stage depth + cost neighborhoods (zero-padded)
    const int NS = Dn * 5 * (PX + 4);          // 1920
    for (int s = tid; s < NS; s += 256) {
        int d  = s / (5 * (PX + 4));
        int r  = s % (5 * (PX + 4));
        int ny = r / (PX + 4);
        int nx = r % (PX + 4);
        int gy = y - 2 + ny;
        int gx = x0 - 2 + nx;
        float dv = 0.0f, cvv = 0.0f;
        if (gy >= 0 && gy < Hn && gx >= 0 && gx < Wn) {
            size_t off = (size_t)(b * Dn + d) * HWn + gy * Wn + gx;
            dv  = depth[off];
            cvv = cv[off];
        }
        sd[d][ny][nx] = dv;
        sc[d][ny][nx] = cvv;
    }
    // stage view-0 feature halo (zero-padded; zero-fill reproduces pad diff)
    for (int s = tid; s < 5 * (PX + 4); s += 256) {
        int ny = s / (PX + 4);
        int nx = s % (PX + 4);
        int gy = y - 2 + ny;
        int gx = x0 - 2 + nx;
        if (gy >= 0 && gy < Hn && gx >= 0 && gx < Wn) {
            const float4* src = (const float4*)(featH +
                ((size_t)(0 * Bn + b) * HWn + gy * Wn + gx) * Cn);
            sfeatv[ny][nx][0] = src[0];
            sfeatv[ny][nx][1] = src[1];
        } else {
            float4 z = make_float4(0.f, 0.f, 0.f, 0.f);
            sfeatv[ny][nx][0] = z;
            sfeatv[ny][nx][1] = z;
        }
    }
    __syncthreads();

    // w_feat: 25 x PX tasks
    for (int s = tid; s < 25 * PX; s += 256) {
        int k   = s / PX;
        int xi2 = s % PX;
        const __half2* ctrp = (const __half2*)&sfeatv[2][xi2 + 2][0];
        const __half2* nbp  = (const __half2*)&sfeatv[k / 5][xi2 + (k % 5)][0];
        float acc = 0.0f;
        #pragma unroll
        for (int j = 0; j < 8; j++) {
            float2 a = __half22float2(nbp[j]);
            float2 c = __half22float2(ctrp[j]);
            float dx0 = a.x - c.x, dy0 = a.y - c.y;
            acc += dx0 * dx0 + dy0 * dy0;
        }
        swf[k][xi2] = sqrtf(acc);
    }
    __syncthreads();

    int xi = tid % PX;
    int d  = tid / PX;

    float ctr = sd[d][2][xi + 2];
    float aarr[25];
    float mx = -3.402823e38f;
    #pragma unroll
    for (int k = 0; k < 25; k++) {
        float dn = sd[d][k / 5][xi + k % 5];
        aarr[k] = fabsf(dn - ctr);
        mx = fmaxf(mx, aarr[k]);
    }
    float den = 0.0f, num = 0.0f;
    #pragma unroll
    for (int k = 0; k < 25; k++) {
        float e = __expf(aarr[k] - mx);
        den += e;
        num += sc[d][k / 5][xi + k % 5] * e * swf[k][xi];
    }
    sagg[d][xi] = num / den;
    __syncthreads();

    // serial softmax over D + expectation: 8 threads, one per pixel
    if (tid < PX) {
        int p = tid;
        float m = -3.402823e38f;
        #pragma unroll
        for (int dd = 0; dd < Dn; dd++)
            m = fmaxf(m, sagg[dd][p]);
        float dn2 = 0.0f, nm2 = 0.0f;
        #pragma unroll
        for (int dd = 0; dd < Dn; dd++) {
            float e = __expf(sagg[dd][p] - m);
            dn2 += e;
            nm2 += e * sd[dd][2][p + 2];
        }
        out[(size_t)(b * Hn + y) * Wn + x0 + p] = nm2 / dn2;
    }
}

// ---------------------------------------------------------------------------
extern "C" void kernel_launch(void* const* d_in, const int* in_sizes, int n_in,
                              void* d_out, int out_size, void* d_ws, size_t ws_size,
                              hipStream_t stream) {
    const float* feat  = (const float*)d_in[0];   // (V,B,C,H,W)
    const float* intr  = (const float*)d_in[1];   // (V,B,3,3)
    const float* c2w   = (const float*)d_in[2];   // (V,B,4,4)
    const float* depth = (const float*)d_in[3];   // (B,D,H,W)
    float* out = (float*)d_out;                   // (B,H,W)

    float* ws    = (float*)d_ws;
    float* proj  = ws;                                        // 64 floats
    __half* featH = (__half*)(ws + 64);                       // V*B*HW*C halfs = 3MB
    float* cv    = ws + 64 + (Vn * Bn * HWn * Cn) / 2;        // B*D*HW floats

    int n_tr = Vn * Bn * HWn;
    transpose_kernel<<<(n_tr + 255) / 256, 256, 0, stream>>>(feat, featH, intr, c2w, proj);

    int n_cost = Bn * (Dn / KD) * HWn;
    cost_kernel<<<(n_cost + 255) / 256, 256, 0, stream>>>(featH, depth, proj, cv);

    int n_blk = Bn * Hn * (Wn / PX);
    aggfinal_kernel<<<n_blk, 256, 0, stream>>>(cv, depth, featH, out);
}